// Round 1
// baseline (323.585 us; speedup 1.0000x reference)
//
#include <hip/hip_runtime.h>

// JME Fairness Loss — MI355X
// Pipeline:
//   K_A : mean(true_scores)                  -> ws.t_sum (double atomic)
//   K_BC: per-row top-100 (exact jax.lax.top_k order) + Gumbel soft-rank
//         exposure; accumulates sum(e), sum(e^2), per-pair-id sum/count
//   K_D : finalize ii = E[e^2]-2tE[e]+t^2, gg from pair bins, total
//
// Gumbel noise reproduces JAX threefry2x32, key = jax.random.key(1) -> (0,1).
// NOISE_VARIANT 0 = partitionable (modern JAX default): bits = o0^o1 of
//   threefry((0,1), (0, i)).  VARIANT 1 = legacy concat path (fallback).
#define NOISE_VARIANT 0

typedef unsigned int u32;
typedef unsigned long long u64;

__device__ __forceinline__ u32 rotl32(u32 x, int r) { return (x << r) | (x >> (32 - r)); }

__device__ __forceinline__ void tf2x32(u32 k0, u32 k1, u32 x0, u32 x1, u32& o0, u32& o1) {
  u32 ks2 = 0x1BD11BDAu ^ k0 ^ k1;
#define TFR(r) { x0 += x1; x1 = rotl32(x1, r); x1 ^= x0; }
  x0 += k0; x1 += k1;
  TFR(13) TFR(15) TFR(26) TFR(6)
  x0 += k1; x1 += ks2 + 1u;
  TFR(17) TFR(29) TFR(16) TFR(24)
  x0 += ks2; x1 += k0 + 2u;
  TFR(13) TFR(15) TFR(26) TFR(6)
  x0 += k0; x1 += k1 + 3u;
  TFR(17) TFR(29) TFR(16) TFR(24)
  x0 += k1; x1 += ks2 + 4u;
  TFR(13) TFR(15) TFR(26) TFR(6)
  x0 += ks2; x1 += k0 + 5u;
#undef TFR
  o0 = x0; o1 = x1;
}

__device__ __forceinline__ u32 gumbel_bits(u32 i) {
#if NOISE_VARIANT == 0
  u32 o0, o1;
  tf2x32(0u, 1u, 0u, i, o0, o1);
  return o0 ^ o1;
#else
  const u32 HALF = 512000u;  // 10*1024*100 / 2
  u32 o0, o1;
  if (i < HALF) { tf2x32(0u, 1u, i, i + HALF, o0, o1); return o0; }
  else          { tf2x32(0u, 1u, i - HALF, i, o0, o1); return o1; }
#endif
}

__device__ __forceinline__ float gumbel_noise(u32 i) {
  u32 bits = gumbel_bits(i);
  float f = __uint_as_float((bits >> 9) | 0x3f800000u) - 1.0f;  // [0,1)
  const float TINY = 1.17549435e-38f;
  float u = fmaxf(TINY, f + TINY);   // uniform(minval=tiny, maxval=1)
  return -logf(-logf(u));
}

// ---------------- Kernel A: mean of true_scores ----------------
__global__ __launch_bounds__(256) void true_mean_kernel(
    const float* __restrict__ ts, double* __restrict__ t_sum, int n) {
  int tid = blockIdx.x * blockDim.x + threadIdx.x;
  int stride = gridDim.x * blockDim.x;
  float local = 0.f;
  const float4* ts4 = (const float4*)ts;
  int n4 = n >> 2;
  for (int i = tid; i < n4; i += stride) {
    float4 v = ts4[i];
    local += (v.x + v.y) + (v.z + v.w);
  }
  for (int i = (n4 << 2) + tid; i < n; i += stride) local += ts[i];
  for (int off = 32; off; off >>= 1) local += __shfl_down(local, off);
  __shared__ float wsum[4];
  int lane = threadIdx.x & 63, wid = threadIdx.x >> 6;
  if (lane == 0) wsum[wid] = local;
  __syncthreads();
  if (threadIdx.x == 0) {
    float s = (wsum[0] + wsum[1]) + (wsum[2] + wsum[3]);
    atomicAdd(t_sum, (double)s);
  }
}

// ---------------- Kernel BC: per-row top-k + exposure ----------------
// one block (256 threads) per row b
__global__ __launch_bounds__(256) void topk_expo_kernel(
    const float* __restrict__ pred,   // [1024][10000]
    const int*   __restrict__ ugrp,   // [1024]
    const int*   __restrict__ igrp,   // [10000]
    double* __restrict__ sum_e, double* __restrict__ sum_e2,
    double* __restrict__ pair_sum, int* __restrict__ pair_cnt) {
  const int N = 10000, K = 100;
  const int b = blockIdx.x;
  const int t = threadIdx.x;

  __shared__ u32 keys[10000];
  __shared__ u32 hist[256];
  __shared__ u64 cand[1024];
  __shared__ float topv[100];
  __shared__ int   pidv[100];
  __shared__ float noisy[100];
  __shared__ float expo[100];
  __shared__ float pairS[128];
  __shared__ int   pairC[128];
  __shared__ float bS, bS2;
  __shared__ u32 cnt_, b0_;

  hist[t] = 0u;
  if (t < 128) { pairS[t] = 0.f; pairC[t] = 0; }
  if (t == 0) { cnt_ = 0u; bS = 0.f; bS2 = 0.f; }
  __syncthreads();

  // 1) monotonic key transform + top-byte histogram
  const float* row = pred + (size_t)b * N;
  for (int i = t; i < N; i += 256) {
    u32 u = __float_as_uint(row[i]);
    u32 key = u ^ ((u & 0x80000000u) ? 0xFFFFFFFFu : 0x80000000u);
    keys[i] = key;
    atomicAdd(&hist[key >> 24], 1u);
  }
  __syncthreads();

  // 2) find threshold byte b0 (cum count from top reaches K)
  if (t == 0) {
    u32 cum = 0, b0 = 0;
    for (int by = 255; by >= 0; --by) {
      u32 c = hist[by];
      if (cum + c >= (u32)K) { b0 = (u32)by; break; }
      cum += c;
    }
    b0_ = b0;
  }
  __syncthreads();
  u32 b0 = b0_;

  // 3) collect candidates (topbyte >= b0); packed (key<<32)|~idx
  for (int i = t; i < N; i += 256) {
    u32 key = keys[i];
    if ((key >> 24) >= b0) {
      u32 pos = atomicAdd(&cnt_, 1u);
      if (pos < 1024u) cand[pos] = ((u64)key << 32) | (u32)(~(u32)i);
    }
  }
  __syncthreads();
  u32 n = min(cnt_, 1024u);
  for (int i = t; i < 1024; i += 256)
    if ((u32)i >= n) cand[i] = 0ull;
  __syncthreads();

  // 4) bitonic sort, descending (key desc, then idx asc via ~idx)
  for (int k = 2; k <= 1024; k <<= 1) {
    for (int j = k >> 1; j > 0; j >>= 1) {
      for (int i = t; i < 1024; i += 256) {
        int ixj = i ^ j;
        if (ixj > i) {
          u64 a = cand[i], c = cand[ixj];
          bool up = (i & k) == 0;
          if (up ? (a < c) : (a > c)) { cand[i] = c; cand[ixj] = a; }
        }
      }
      __syncthreads();
    }
  }

  // 5) unpack top-100: value + pair id
  int ug = ugrp[b];
  if (t < K) {
    u64 p = cand[t];
    u32 key = (u32)(p >> 32);
    u32 idx = ~(u32)p;
    u32 u = (key & 0x80000000u) ? (key ^ 0x80000000u) : ~key;
    topv[t] = __uint_as_float(u);
    pidv[t] = ug * 16 + igrp[idx];
    expo[t] = 0.f;
  }
  __syncthreads();

  // 6) 10 Gumbel samples: pairwise soft-rank -> exposure accumulation
  for (int s = 0; s < 10; ++s) {
    if (t < K) {
      u32 i = ((u32)s * 1024u + (u32)b) * 100u + (u32)t;
      noisy[t] = topv[t] + gumbel_noise(i);
    }
    __syncthreads();
    if (t < 2 * K) {
      int j = t >> 1, half = t & 1;
      float nj = noisy[j];
      float S = 0.f;
      int l0 = half * 50;
#pragma unroll 10
      for (int l = l0; l < l0 + 50; ++l) {
        float d = (nj - noisy[l]) * 10.0f;          // diffs / TAU
        S += 1.0f / (1.0f + __expf(-d));            // sigmoid
      }
      S += __shfl_xor(S, 1);
      if (half == 0) {
        float rank_m1 = S - 0.5f;                   // ranks - 1
        expo[j] += exp2f(rank_m1 * -0.3219280948873623f);  // 0.8^rank_m1
      }
    }
    __syncthreads();
  }

  // 7) accumulate block sums
  if (t < K) {
    float e = expo[t] / 10.0f;     // mean over samples
    atomicAdd(&pairS[pidv[t]], e);
    atomicAdd(&pairC[pidv[t]], 1);
    atomicAdd(&bS, e);
    atomicAdd(&bS2, e * e);
  }
  __syncthreads();
  if (t < 128 && pairC[t] > 0) {
    atomicAdd(&pair_sum[t], (double)pairS[t]);
    atomicAdd(&pair_cnt[t], pairC[t]);
  }
  if (t == 0) {
    atomicAdd(sum_e, (double)bS);
    atomicAdd(sum_e2, (double)bS2);
  }
}

// ---------------- Kernel D: finalize ----------------
__global__ void finalize_kernel(const double* __restrict__ t_sum,
                                const double* __restrict__ sum_e,
                                const double* __restrict__ sum_e2,
                                const double* __restrict__ pair_sum,
                                const int* __restrict__ pair_cnt,
                                float* __restrict__ out) {
  if (threadIdx.x == 0 && blockIdx.x == 0) {
    double t = *t_sum / 10240000.0;            // mean(true_scores)
    double me = *sum_e / 102400.0;             // E[exposure]
    double me2 = *sum_e2 / 102400.0;           // E[exposure^2]
    double ii = me2 - 2.0 * t * me + t * t;    // mean((e-t)^2)
    double gg = 0.0;
    for (int p = 0; p < 128; ++p) {
      int c = pair_cnt[p];
      if (c > 0) {
        double avg = (pair_sum[p] - (double)c * t) / (double)c;
        gg += avg * avg;
      }
    }
    gg /= 128.0;
    out[0] = (float)(ii + gg);
    out[1] = (float)ii;
    out[2] = (float)gg;
  }
}

extern "C" void kernel_launch(void* const* d_in, const int* in_sizes, int n_in,
                              void* d_out, int out_size, void* d_ws, size_t ws_size,
                              hipStream_t stream) {
  (void)in_sizes; (void)n_in; (void)out_size; (void)ws_size;
  const float* pred = (const float*)d_in[0];
  const float* ts   = (const float*)d_in[1];
  const int*   ugrp = (const int*)d_in[2];
  const int*   igrp = (const int*)d_in[3];
  float* out = (float*)d_out;

  // ws layout (doubles first): t_sum, sum_e, sum_e2, pair_sum[128], pair_cnt[128]
  double* t_sum    = (double*)d_ws;
  double* sum_e    = t_sum + 1;
  double* sum_e2   = t_sum + 2;
  double* pair_sum = t_sum + 3;
  int*    pair_cnt = (int*)(t_sum + 3 + 128);

  hipMemsetAsync(d_ws, 0, (3 + 128) * sizeof(double) + 128 * sizeof(int), stream);

  true_mean_kernel<<<2048, 256, 0, stream>>>(ts, t_sum, 1024 * 10000);
  topk_expo_kernel<<<1024, 256, 0, stream>>>(pred, ugrp, igrp,
                                             sum_e, sum_e2, pair_sum, pair_cnt);
  finalize_kernel<<<1, 64, 0, stream>>>(t_sum, sum_e, sum_e2, pair_sum, pair_cnt, out);
}

// Round 3
// 207.974 us; speedup vs baseline: 1.5559x; 1.5559x over previous
//
#include <hip/hip_runtime.h>

// JME Fairness Loss — MI355X, round 3 (re-run of round-2 design; R2 bench was
// an infra failure, not a kernel result)
// Fused pipeline (one main kernel, 1024 blocks x 256 thr, all-resident):
//   per row b: ts-row-sum | radix-select top-100 (exact jax.lax.top_k order)
//              | 128-bitonic sort | Gumbel soft-rank exposure (all threads)
//   finalize kernel: ii = E[e^2]-2tE[e]+t^2, gg from 128 pair bins.
// Gumbel = JAX partitionable threefry2x32, key (0,1)  [verified absmax 0.0 in R1]

typedef unsigned int u32;
typedef unsigned long long u64;

__device__ __forceinline__ u32 rotl32(u32 x, int r) { return (x << r) | (x >> (32 - r)); }

__device__ __forceinline__ void tf2x32(u32 k0, u32 k1, u32 x0, u32 x1, u32& o0, u32& o1) {
  u32 ks2 = 0x1BD11BDAu ^ k0 ^ k1;
#define TFR(r) { x0 += x1; x1 = rotl32(x1, r); x1 ^= x0; }
  x0 += k0; x1 += k1;
  TFR(13) TFR(15) TFR(26) TFR(6)
  x0 += k1; x1 += ks2 + 1u;
  TFR(17) TFR(29) TFR(16) TFR(24)
  x0 += ks2; x1 += k0 + 2u;
  TFR(13) TFR(15) TFR(26) TFR(6)
  x0 += k0; x1 += k1 + 3u;
  TFR(17) TFR(29) TFR(16) TFR(24)
  x0 += k1; x1 += ks2 + 4u;
  TFR(13) TFR(15) TFR(26) TFR(6)
  x0 += ks2; x1 += k0 + 5u;
#undef TFR
  o0 = x0; o1 = x1;
}

__device__ __forceinline__ float gumbel_noise(u32 i) {
  u32 o0, o1;
  tf2x32(0u, 1u, 0u, i, o0, o1);
  u32 bits = o0 ^ o1;
  float f = __uint_as_float((bits >> 9) | 0x3f800000u) - 1.0f;  // [0,1)
  const float TINY = 1.17549435e-38f;
  float u = fmaxf(TINY, f + TINY);
  return -logf(-logf(u));
}

__device__ __forceinline__ u32 fkey(float v) {
  u32 u = __float_as_uint(v);
  return u ^ ((u & 0x80000000u) ? 0xFFFFFFFFu : 0x80000000u);  // order-preserving
}

// ---------------- fused main kernel: one block per row ----------------
__global__ __launch_bounds__(256) void fused_kernel(
    const float* __restrict__ pred,   // [1024][10000]
    const float* __restrict__ ts,     // [1024][10000]
    const int*   __restrict__ ugrp,   // [1024]
    const int*   __restrict__ igrp,   // [10000]
    double* __restrict__ t_sum,
    double* __restrict__ sum_e, double* __restrict__ sum_e2,
    double* __restrict__ pair_sum, int* __restrict__ pair_cnt) {
  const int N = 10000, N4 = 2500, K = 100;
  const int b = blockIdx.x;
  const int t = threadIdx.x;

  __shared__ u32 hist[256];
  __shared__ u32 ckey[1024];
  __shared__ u64 sbuf[128];
  __shared__ float topv[100];
  __shared__ int   pidv[100];
  __shared__ __align__(16) float noisy[1000];   // [10][100]
  __shared__ float expo[100];
  __shared__ float pairS[128];
  __shared__ int   pairC[128];
  __shared__ float wred[4];
  __shared__ u32 sh_cnt, sh_n2, sh_T, sh_A, sh_done;
  __shared__ float sh_bS, sh_bS2;

  hist[t] = 0u;
  if (t < 128) { pairS[t] = 0.f; pairC[t] = 0; }
  if (t < 100) expo[t] = 0.f;
  if (t == 0) { sh_cnt = 0u; sh_n2 = 0u; sh_done = 0u; sh_bS = 0.f; sh_bS2 = 0.f; }
  __syncthreads();

  const float4* row4 = (const float4*)(pred + (size_t)b * N);
  const float4* tsr4 = (const float4*)(ts + (size_t)b * N);

  // --- scan A: top-byte histogram of keys  +  ts row sum ---
  float tsum = 0.f;
  for (int i4 = t; i4 < N4; i4 += 256) {
    float4 p = row4[i4];
    float4 q = tsr4[i4];
    tsum += (q.x + q.y) + (q.z + q.w);
    atomicAdd(&hist[fkey(p.x) >> 24], 1u);
    atomicAdd(&hist[fkey(p.y) >> 24], 1u);
    atomicAdd(&hist[fkey(p.z) >> 24], 1u);
    atomicAdd(&hist[fkey(p.w) >> 24], 1u);
  }
  for (int off = 32; off; off >>= 1) tsum += __shfl_down(tsum, off);
  if ((t & 63) == 0) wred[t >> 6] = tsum;
  __syncthreads();
  if (t == 0) {
    atomicAdd(t_sum, (double)((wred[0] + wred[1]) + (wred[2] + wred[3])));
    // round 1: pick top byte
    u32 cum = 0, b0 = 255;
    for (int v = 255; v >= 0; --v) {
      u32 c = hist[v];
      if (cum + c >= 100u) { b0 = (u32)v; break; }
      cum += c;
    }
    sh_A = cum;                  // count strictly above byte b0
    sh_T = b0 << 24;
    sh_done = (cum + hist[b0] <= 128u) ? 1u : 0u;
  }
  __syncthreads();

  // --- radix refinement on bytes 2..0 (operates on compacted b0-bin keys) ---
  if (!sh_done) {
    u32 b0 = sh_T >> 24;
    for (int i4 = t; i4 < N4; i4 += 256) {
      float4 p = row4[i4];
#pragma unroll
      for (int c = 0; c < 4; ++c) {
        float v = c == 0 ? p.x : c == 1 ? p.y : c == 2 ? p.z : p.w;
        u32 key = fkey(v);
        if ((key >> 24) == b0) {
          u32 pos = atomicAdd(&sh_cnt, 1u);
          if (pos < 1024u) ckey[pos] = key;
        }
      }
    }
    __syncthreads();
    u32 nk = sh_cnt < 1024u ? sh_cnt : 1024u;
    for (int shift = 16; shift >= 0; shift -= 8) {
      hist[t] = 0u;
      __syncthreads();
      u32 prefhi = sh_T >> (shift + 8);
      for (int i = t; i < (int)nk; i += 256) {
        u32 key = ckey[i];
        if ((key >> (shift + 8)) == prefhi) atomicAdd(&hist[(key >> shift) & 0xFFu], 1u);
      }
      __syncthreads();
      if (t == 0) {
        u32 target = 100u - sh_A;
        u32 cum = 0, bb = 255;
        for (int v = 255; v >= 0; --v) {
          u32 c = hist[v];
          if (cum + c >= target) { bb = (u32)v; break; }
          cum += c;
        }
        sh_A += cum;
        sh_T |= (u32)bb << shift;
        sh_done = (sh_A + hist[bb] <= 128u || shift == 0) ? 1u : 0u;
      }
      __syncthreads();
      if (sh_done) break;
    }
  }

  // --- final collect: all items with key >= T  (count in (99,128]) ---
  {
    u32 T = sh_T;
    for (int i4 = t; i4 < N4; i4 += 256) {
      float4 p = row4[i4];
#pragma unroll
      for (int c = 0; c < 4; ++c) {
        int i = i4 * 4 + c;
        float v = c == 0 ? p.x : c == 1 ? p.y : c == 2 ? p.z : p.w;
        u32 key = fkey(v);
        if (key >= T) {
          u32 pos = atomicAdd(&sh_n2, 1u);
          if (pos < 128u) sbuf[pos] = ((u64)key << 32) | (u32)(~(u32)i);
        }
      }
    }
    __syncthreads();
    u32 n2 = sh_n2 < 128u ? sh_n2 : 128u;
    if (t < 128 && (u32)t >= n2) sbuf[t] = 0ull;
    __syncthreads();
  }

  // --- bitonic sort 128, descending (key desc, idx asc via ~idx) ---
  for (int k = 2; k <= 128; k <<= 1) {
    for (int j = k >> 1; j > 0; j >>= 1) {
      if (t < 128) {
        int ixj = t ^ j;
        if (ixj > t) {
          u64 a = sbuf[t], c2 = sbuf[ixj];
          bool up = (t & k) == 0;
          if (up ? (a < c2) : (a > c2)) { sbuf[t] = c2; sbuf[ixj] = a; }
        }
      }
      __syncthreads();
    }
  }

  // --- unpack top-100 ---
  int ug = ugrp[b];
  if (t < K) {
    u64 p = sbuf[t];
    u32 key = (u32)(p >> 32);
    u32 idx = ~(u32)p;
    u32 u = (key & 0x80000000u) ? (key ^ 0x80000000u) : ~key;
    topv[t] = __uint_as_float(u);
    pidv[t] = ug * 16 + igrp[idx];
  }
  __syncthreads();

  // --- Gumbel noise fill: 1000 items (10 samples x 100) ---
  for (int si = t; si < 1000; si += 256) {
    int s = si / 100, i = si - s * 100;
    noisy[si] = topv[i] + gumbel_noise(((u32)s * 1024u + (u32)b) * 100u + (u32)i);
  }
  __syncthreads();

  // --- soft-rank + exposure: thread handles (s,i) work items ---
  const float C2 = 14.426950408889634f;    // (1/tau) * log2(e) = 10*log2e
  const float LG = -0.32192809488736235f;  // log2(0.8)
  for (int si = t; si < 1000; si += 256) {
    int s = si / 100, i = si - s * 100;
    float nv = noisy[si];
    float nvC = nv * C2;
    const float* nrow = &noisy[s * 100];
    float S = 0.f;
#pragma unroll 4
    for (int j = 0; j < 100; ++j) {
      // sigmoid((nv-nj)*10) = 1/(1+exp2((nj-nv)*10*log2e))
      float a = __builtin_fmaf(nrow[j], C2, -nvC);
      S += __builtin_amdgcn_rcpf(1.0f + exp2f(a));
    }
    float ex = exp2f((S - 0.5f) * LG);     // gamma^(rank-1)
    atomicAdd(&expo[i], ex);
  }
  __syncthreads();

  // --- block accumulation ---
  if (t < K) {
    float e = expo[t] * 0.1f;   // mean over 10 samples
    atomicAdd(&pairS[pidv[t]], e);
    atomicAdd(&pairC[pidv[t]], 1);
    atomicAdd(&sh_bS, e);
    atomicAdd(&sh_bS2, e * e);
  }
  __syncthreads();
  if (t < 128 && pairC[t] > 0) {
    atomicAdd(&pair_sum[t], (double)pairS[t]);
    atomicAdd(&pair_cnt[t], pairC[t]);
  }
  if (t == 0) {
    atomicAdd(sum_e, (double)sh_bS);
    atomicAdd(sum_e2, (double)sh_bS2);
  }
}

// ---------------- finalize ----------------
__global__ void finalize_kernel(const double* __restrict__ t_sum,
                                const double* __restrict__ sum_e,
                                const double* __restrict__ sum_e2,
                                const double* __restrict__ pair_sum,
                                const int* __restrict__ pair_cnt,
                                float* __restrict__ out) {
  if (threadIdx.x == 0 && blockIdx.x == 0) {
    double t = *t_sum / 10240000.0;
    double me = *sum_e / 102400.0;
    double me2 = *sum_e2 / 102400.0;
    double ii = me2 - 2.0 * t * me + t * t;
    double gg = 0.0;
    for (int p = 0; p < 128; ++p) {
      int c = pair_cnt[p];
      if (c > 0) {
        double avg = (pair_sum[p] - (double)c * t) / (double)c;
        gg += avg * avg;
      }
    }
    gg /= 128.0;
    out[0] = (float)(ii + gg);
    out[1] = (float)ii;
    out[2] = (float)gg;
  }
}

extern "C" void kernel_launch(void* const* d_in, const int* in_sizes, int n_in,
                              void* d_out, int out_size, void* d_ws, size_t ws_size,
                              hipStream_t stream) {
  (void)in_sizes; (void)n_in; (void)out_size; (void)ws_size;
  const float* pred = (const float*)d_in[0];
  const float* ts   = (const float*)d_in[1];
  const int*   ugrp = (const int*)d_in[2];
  const int*   igrp = (const int*)d_in[3];
  float* out = (float*)d_out;

  double* t_sum    = (double*)d_ws;
  double* sum_e    = t_sum + 1;
  double* sum_e2   = t_sum + 2;
  double* pair_sum = t_sum + 3;
  int*    pair_cnt = (int*)(t_sum + 3 + 128);

  hipMemsetAsync(d_ws, 0, (3 + 128) * sizeof(double) + 128 * sizeof(int), stream);

  fused_kernel<<<1024, 256, 0, stream>>>(pred, ts, ugrp, igrp,
                                         t_sum, sum_e, sum_e2, pair_sum, pair_cnt);
  finalize_kernel<<<1, 64, 0, stream>>>(t_sum, sum_e, sum_e2, pair_sum, pair_cnt, out);
}

// Round 4
// 167.769 us; speedup vs baseline: 1.9288x; 1.2396x over previous
//
#include <hip/hip_runtime.h>

// JME Fairness Loss — MI355X, round 4
// 512-thr blocks (32 waves/CU = 100% occ cap), wave0 shuffle-scan bin select,
// LDS candidate compaction (no repeated row scans), 2-barrier rank sort,
// float4 sigmoid reads, parallel finalize.
// Gumbel = JAX partitionable threefry2x32, key (0,1)  [absmax 0.0 in R1/R3]

typedef unsigned int u32;
typedef unsigned long long u64;

__device__ __forceinline__ u32 rotl32(u32 x, int r) { return (x << r) | (x >> (32 - r)); }

__device__ __forceinline__ void tf2x32(u32 k0, u32 k1, u32 x0, u32 x1, u32& o0, u32& o1) {
  u32 ks2 = 0x1BD11BDAu ^ k0 ^ k1;
#define TFR(r) { x0 += x1; x1 = rotl32(x1, r); x1 ^= x0; }
  x0 += k0; x1 += k1;
  TFR(13) TFR(15) TFR(26) TFR(6)
  x0 += k1; x1 += ks2 + 1u;
  TFR(17) TFR(29) TFR(16) TFR(24)
  x0 += ks2; x1 += k0 + 2u;
  TFR(13) TFR(15) TFR(26) TFR(6)
  x0 += k0; x1 += k1 + 3u;
  TFR(17) TFR(29) TFR(16) TFR(24)
  x0 += k1; x1 += ks2 + 4u;
  TFR(13) TFR(15) TFR(26) TFR(6)
  x0 += ks2; x1 += k0 + 5u;
#undef TFR
  o0 = x0; o1 = x1;
}

__device__ __forceinline__ float gumbel_noise(u32 i) {
  u32 o0, o1;
  tf2x32(0u, 1u, 0u, i, o0, o1);
  u32 bits = o0 ^ o1;
  float f = __uint_as_float((bits >> 9) | 0x3f800000u) - 1.0f;  // [0,1)
  const float TINY = 1.17549435e-38f;
  float u = fmaxf(TINY, f + TINY);
  return -logf(-logf(u));
}

__device__ __forceinline__ u32 fkey(float v) {
  u32 u = __float_as_uint(v);
  return u ^ ((u & 0x80000000u) ? 0xFFFFFFFFu : 0x80000000u);  // order-preserving
}

// wave-0 (lanes 0..63) bin selection over hist[256] via shuffle suffix scan.
// Finds largest bin v with count-at-or-above(v) >= target (target = 100 - *sh_A).
// Updates sh_T (|= v<<shift), sh_A (+= count strictly above v at this level),
// sh_done ((A+cnt<=128) || shift==0).
__device__ __forceinline__ void select_bin(const u32* __restrict__ hist, int shift,
                                           u32* sh_T, u32* sh_A, u32* sh_done,
                                           int lane) {
  u32 prevA = *sh_A;
  u32 target = 100u - prevA;
  u32 c0 = hist[lane * 4 + 0], c1 = hist[lane * 4 + 1];
  u32 c2 = hist[lane * 4 + 2], c3 = hist[lane * 4 + 3];
  u32 s = c0 + c1 + c2 + c3;
  u32 suf = s;  // inclusive suffix sum over lanes
#pragma unroll
  for (int off = 1; off < 64; off <<= 1) {
    u32 o = __shfl_down(suf, off);
    suf += (lane + off < 64) ? o : 0u;
  }
  u32 sufx = suf - s;  // count in bins above this lane's 4 bins
  if (sufx < target && suf >= target) {   // exactly one lane
    u32 cc[4] = {c0, c1, c2, c3};
    u32 acc = sufx, bin = 0, cnt = 0;
#pragma unroll
    for (int k = 3; k >= 0; --k) {
      if (acc + cc[k] >= target) { bin = (u32)(lane * 4 + k); cnt = cc[k]; break; }
      acc += cc[k];
    }
    u32 newA = prevA + acc;
    *sh_T = *sh_T | (bin << shift);
    *sh_A = newA;
    *sh_done = (newA + cnt <= 128u || shift == 0) ? 1u : 0u;
  }
}

// ---------------- fused main kernel: one block (512 thr) per row ----------------
__global__ __launch_bounds__(512, 8) void fused_kernel(
    const float* __restrict__ pred,   // [1024][10000]
    const float* __restrict__ ts,     // [1024][10000]
    const int*   __restrict__ ugrp,   // [1024]
    const int*   __restrict__ igrp,   // [10000]
    double* __restrict__ t_sum,
    double* __restrict__ sum_e, double* __restrict__ sum_e2,
    double* __restrict__ pair_sum, int* __restrict__ pair_cnt) {
  const int N = 10000, N4 = 2500, K = 100;
  const int b = blockIdx.x;
  const int t = threadIdx.x;

  __shared__ u32 hist4[4][256];
  __shared__ u64 cand[2048];
  __shared__ u64 sbuf[128];
  __shared__ u64 sorted[128];
  __shared__ u32 rankv[128];
  __shared__ float topv[100];
  __shared__ int   pidv[100];
  __shared__ __align__(16) float noisy[1000];   // [10][100], rows 400B -> f4-aligned
  __shared__ float expo[100];
  __shared__ float pairS[128];
  __shared__ int   pairC[128];
  __shared__ float wred[8];
  __shared__ u32 sh_cnt, sh_nc, sh_T, sh_A, sh_done, sh_ovf;
  __shared__ float sh_bS, sh_bS2;

  if (t < 256) { hist4[0][t] = 0u; hist4[1][t] = 0u; hist4[2][t] = 0u; hist4[3][t] = 0u; }
  if (t < 128) { pairS[t] = 0.f; pairC[t] = 0; rankv[t] = 0u; }
  if (t < 100) expo[t] = 0.f;
  if (t == 0) { sh_cnt = 0u; sh_nc = 0u; sh_T = 0u; sh_A = 0u; sh_done = 0u; sh_ovf = 0u;
                sh_bS = 0.f; sh_bS2 = 0.f; }
  __syncthreads();

  const float4* __restrict__ row4 = (const float4*)(pred + (size_t)b * N);
  const float4* __restrict__ tsr4 = (const float4*)(ts + (size_t)b * N);

  // ---- pass 1 (HBM): top-byte histogram + ts row sum ----
  float tsum = 0.f;
  u32* myh = hist4[(t >> 7) & 3];
#pragma unroll
  for (int k = 0; k < 5; ++k) {
    int i4 = t + (k << 9);
    if (k == 4 && i4 >= N4) break;
    float4 pp = row4[i4];
    float4 qq = tsr4[i4];
    tsum += (qq.x + qq.y) + (qq.z + qq.w);
    atomicAdd(&myh[fkey(pp.x) >> 24], 1u);
    atomicAdd(&myh[fkey(pp.y) >> 24], 1u);
    atomicAdd(&myh[fkey(pp.z) >> 24], 1u);
    atomicAdd(&myh[fkey(pp.w) >> 24], 1u);
  }
#pragma unroll
  for (int off = 32; off; off >>= 1) tsum += __shfl_down(tsum, off);
  if ((t & 63) == 0) wred[t >> 6] = tsum;
  __syncthreads();
  if (t == 0) {
    float s8 = 0.f;
#pragma unroll
    for (int w = 0; w < 8; ++w) s8 += wred[w];
    atomicAdd(t_sum, (double)s8);
  }
  if (t < 256) hist4[0][t] += hist4[1][t] + hist4[2][t] + hist4[3][t];
  __syncthreads();

  if (t < 64) select_bin(&hist4[0][0], 24, &sh_T, &sh_A, &sh_done, t);
  __syncthreads();

  bool r1done = (sh_done != 0u);
  bool use_cand = false;
  u32 nc = 0;

  if (!r1done) {
    // ---- pass 2 (L2): compact (key,~idx) for top-byte >= b0 ----
    u32 b0 = sh_T >> 24;
    for (int i4 = t; i4 < N4; i4 += 512) {
      float4 pp = row4[i4];
#pragma unroll
      for (int c = 0; c < 4; ++c) {
        float v = (c == 0) ? pp.x : (c == 1) ? pp.y : (c == 2) ? pp.z : pp.w;
        u32 key = fkey(v);
        if ((key >> 24) >= b0) {
          u32 pos = atomicAdd(&sh_cnt, 1u);
          int idx = i4 * 4 + c;
          if (pos < 2048u) cand[pos] = ((u64)key << 32) | (u32)(~(u32)idx);
          else sh_ovf = 1u;
        }
      }
    }
    __syncthreads();
    nc = sh_cnt < 2048u ? sh_cnt : 2048u;
    use_cand = (sh_ovf == 0u);

    // ---- radix refinement (bytes 2..0) over candidates ----
    for (int shift = 16; ; shift -= 8) {
      if (t < 256) hist4[0][t] = 0u;
      __syncthreads();
      u32 pref = sh_T >> (shift + 8);
      if (use_cand) {
        for (int i = t; i < (int)nc; i += 512) {
          u32 key = (u32)(cand[i] >> 32);
          if ((key >> (shift + 8)) == pref) atomicAdd(&hist4[0][(key >> shift) & 255u], 1u);
        }
      } else {  // overflow fallback: re-scan row (correct, slower; never hit on this data)
        for (int i4 = t; i4 < N4; i4 += 512) {
          float4 pp = row4[i4];
#pragma unroll
          for (int c = 0; c < 4; ++c) {
            float v = (c == 0) ? pp.x : (c == 1) ? pp.y : (c == 2) ? pp.z : pp.w;
            u32 key = fkey(v);
            if ((key >> (shift + 8)) == pref) atomicAdd(&hist4[0][(key >> shift) & 255u], 1u);
          }
        }
      }
      __syncthreads();
      if (t < 64) select_bin(&hist4[0][0], shift, &sh_T, &sh_A, &sh_done, t);
      __syncthreads();
      if (sh_done) break;
    }
  }

  // ---- final collect: keys >= T into sbuf (100..128 entries) ----
  {
    u32 T = sh_T;
    if (use_cand) {
      for (int i = t; i < (int)nc; i += 512) {
        u64 p = cand[i];
        if ((u32)(p >> 32) >= T) {
          u32 pos = atomicAdd(&sh_nc, 1u);
          if (pos < 128u) sbuf[pos] = p;
        }
      }
    } else {
      for (int i4 = t; i4 < N4; i4 += 512) {
        float4 pp = row4[i4];
#pragma unroll
        for (int c = 0; c < 4; ++c) {
          float v = (c == 0) ? pp.x : (c == 1) ? pp.y : (c == 2) ? pp.z : pp.w;
          u32 key = fkey(v);
          if (key >= T) {
            u32 pos = atomicAdd(&sh_nc, 1u);
            int idx = i4 * 4 + c;
            if (pos < 128u) sbuf[pos] = ((u64)key << 32) | (u32)(~(u32)idx);
          }
        }
      }
    }
    __syncthreads();
    u32 nreal = sh_nc < 128u ? sh_nc : 128u;
    if (t < 128 && (u32)t >= nreal) sbuf[t] = 0ull;
    __syncthreads();
  }

  // ---- rank sort (descending; u64 keys distinct among real entries) ----
  {
    int e = t >> 2, seg = t & 3;
    u64 mykey = sbuf[e];
    u32 cnt = 0;
    int j0 = seg * 32;
#pragma unroll 8
    for (int j = j0; j < j0 + 32; ++j) cnt += (sbuf[j] > mykey) ? 1u : 0u;
    if (cnt) atomicAdd(&rankv[e], cnt);
    __syncthreads();
    if (t < 128) sorted[rankv[t]] = sbuf[t];   // pads collide harmlessly past rank 99
    __syncthreads();
  }

  // ---- unpack top-100 ----
  int ug = ugrp[b];
  if (t < K) {
    u64 pk = sorted[t];
    u32 key = (u32)(pk >> 32);
    u32 idx = ~(u32)pk;
    u32 u = (key & 0x80000000u) ? (key ^ 0x80000000u) : ~key;
    topv[t] = __uint_as_float(u);
    pidv[t] = ug * 16 + igrp[idx];
  }
  __syncthreads();

  // ---- Gumbel noise: 1000 = 10 samples x 100 ----
  for (int si = t; si < 1000; si += 512) {
    int s = si / 100, i = si - s * 100;
    noisy[si] = topv[i] + gumbel_noise(((u32)s * 1024u + (u32)b) * 100u + (u32)i);
  }
  __syncthreads();

  // ---- soft-rank + exposure (float4 LDS reads) ----
  const float C2 = 14.426950408889634f;    // (1/tau) * log2(e)
  const float LG = -0.32192809488736235f;  // log2(0.8)
  for (int si = t; si < 1000; si += 512) {
    int s = si / 100, i = si - s * 100;
    float nvC = noisy[si] * C2;
    const float4* nr4 = (const float4*)(noisy + s * 100);
    float S = 0.f;
#pragma unroll 5
    for (int jc = 0; jc < 25; ++jc) {
      float4 nj = nr4[jc];
      S += __builtin_amdgcn_rcpf(1.0f + exp2f(__builtin_fmaf(nj.x, C2, -nvC)));
      S += __builtin_amdgcn_rcpf(1.0f + exp2f(__builtin_fmaf(nj.y, C2, -nvC)));
      S += __builtin_amdgcn_rcpf(1.0f + exp2f(__builtin_fmaf(nj.z, C2, -nvC)));
      S += __builtin_amdgcn_rcpf(1.0f + exp2f(__builtin_fmaf(nj.w, C2, -nvC)));
    }
    float ex = exp2f((S - 0.5f) * LG);     // gamma^(rank-1)
    atomicAdd(&expo[i], ex);
  }
  __syncthreads();

  // ---- block accumulation ----
  if (t < K) {
    float e = expo[t] * 0.1f;
    atomicAdd(&pairS[pidv[t]], e);
    atomicAdd(&pairC[pidv[t]], 1);
    atomicAdd(&sh_bS, e);
    atomicAdd(&sh_bS2, e * e);
  }
  __syncthreads();
  if (t < 128 && pairC[t] > 0) {
    atomicAdd(&pair_sum[t], (double)pairS[t]);
    atomicAdd(&pair_cnt[t], pairC[t]);
  }
  if (t == 0) {
    atomicAdd(sum_e, (double)sh_bS);
    atomicAdd(sum_e2, (double)sh_bS2);
  }
}

// ---------------- finalize (parallel, 128 thr) ----------------
__global__ __launch_bounds__(128) void finalize_kernel(
    const double* __restrict__ t_sum, const double* __restrict__ sum_e,
    const double* __restrict__ sum_e2, const double* __restrict__ pair_sum,
    const int* __restrict__ pair_cnt, float* __restrict__ out) {
  int t = threadIdx.x;
  __shared__ double red[128];
  double tmean = *t_sum / 10240000.0;
  double g = 0.0;
  int c = pair_cnt[t];
  if (c > 0) {
    double avg = (pair_sum[t] - (double)c * tmean) / (double)c;
    g = avg * avg;
  }
  red[t] = g;
  __syncthreads();
#pragma unroll
  for (int off = 64; off; off >>= 1) {
    if (t < off) red[t] += red[t + off];
    __syncthreads();
  }
  if (t == 0) {
    double gg = red[0] / 128.0;
    double me = *sum_e / 102400.0;
    double me2 = *sum_e2 / 102400.0;
    double ii = me2 - 2.0 * tmean * me + tmean * tmean;
    out[0] = (float)(ii + gg);
    out[1] = (float)ii;
    out[2] = (float)gg;
  }
}

extern "C" void kernel_launch(void* const* d_in, const int* in_sizes, int n_in,
                              void* d_out, int out_size, void* d_ws, size_t ws_size,
                              hipStream_t stream) {
  (void)in_sizes; (void)n_in; (void)out_size; (void)ws_size;
  const float* pred = (const float*)d_in[0];
  const float* ts   = (const float*)d_in[1];
  const int*   ugrp = (const int*)d_in[2];
  const int*   igrp = (const int*)d_in[3];
  float* out = (float*)d_out;

  double* t_sum    = (double*)d_ws;
  double* sum_e    = t_sum + 1;
  double* sum_e2   = t_sum + 2;
  double* pair_sum = t_sum + 3;
  int*    pair_cnt = (int*)(t_sum + 3 + 128);

  hipMemsetAsync(d_ws, 0, (3 + 128) * sizeof(double) + 128 * sizeof(int), stream);

  fused_kernel<<<1024, 512, 0, stream>>>(pred, ts, ugrp, igrp,
                                         t_sum, sum_e, sum_e2, pair_sum, pair_cnt);
  finalize_kernel<<<1, 128, 0, stream>>>(t_sum, sum_e, sum_e2, pair_sum, pair_cnt, out);
}